// Round 4
// baseline (591.141 us; speedup 1.0000x reference)
//
#include <hip/hip_runtime.h>

// GR4J daily hydrological model, round 10: de-transcendentalized r-chain.
// T=4015 steps, WARMUP=365, B=2048 basins, 32 blocks x 256 threads.
//
// R9 (4-stage pipeline, stripped waves) landed at 313 us = 187 cyc/step.
// w3 = {ds_read + r-chain + store} alone sets the wall => the r-chain's
// serial dependence (rn -> sqrt(rx) -> gex -> r2 -> r2^4 -> sqrt -> rsq)
// with 3 CHAINED transcendentals is the bottleneck: 187 ~= 3*T + 40 =>
// T ~= 45-50 cyc dep latency per trans op.
//
// R10 changes ONLY w3 (w0/w1/w2 byte-identical to R9 for attribution):
//  - state (rx, h): rx = r/x3, h = sqrt(rx). gex = x2*rx^3.5 = x2*h^7
//    (3 mults, trans #1 gone from the chain).
//  - (1+zeta)^(-1/4) via v = (1+zeta)^(-1/8) deg-16 Taylor about 1.5
//    (valid zeta in [0,3], |err| <= ~5e-6; coeffs from exact binomial
//    recurrence in double at init), w = v^2. Trans #2/#3 replaced by
//    ~20 FMA that run IN PARALLEL with the one remaining sqrt(rx2).
//  - h_next = sqrt(rx2) * v; rx_next = rx2 * v^2;
//    qr = x3*(rx2 - rx_next); qd = max(0, q1 + x2*h^7).
//  - zeta > 3 (pathological basins; hard bound ~10) -> exact
//    (1+zeta)^(-1/8) fallback behind an __any() SCALAR branch (never
//    taken in practice; scalar branch prevents if-conversion from
//    putting the 3-trans chain back on the critical path).
// New w3 chain: 1 trans + ~10 VALU ~= 74-90 cyc/step.
//
// Pipeline (unchanged from R9):
//   w0: input staging, global_load_lds size=16, counted vmcnt(11).
//   w1: s-chain -> pr (prring).
//   w2: 9-tap UH conv -> packed (q9,q1) (qring); t=365 history reset.
//   w3: r-chain + store.
// Flags: w1/w2 RELEASE (no vmem), w0/w3 RELAXED + explicit waitcnt.
// Dump/real WAW ordering: one-time vmcnt(0) in w3 at chunks 33, 34.
//
// Approximations (threshold 3.97e-2; absmax was 7.8e-3 bit-stable R7-R9;
// R10's poly routing moves it slightly -- predict <= 2e-2):
//  - tanh(x) ~= x for x<=0.01; (1+z)^(-1/4) 3-term series in prod;
//  - rpe = 1/(dp*de) cubic series (u<=0.0202, err<=1.7e-7);
//  - routing (1+zeta)^(-1/8) deg-16 poly, err <= ~5e-6 (zeta<=3).

#define T_TOTAL 4015
#define NWARM   365
#define NB      2048
#define CH      11          // pipeline chunk: 11 steps
#define NCHUNK  365         // 365 * 11 = 4015

typedef __attribute__((address_space(3))) float       lds_f;
typedef __attribute__((address_space(1))) const float glb_f;

__device__ __forceinline__ void gl_lds_16(const float* g, float* l) {
    // async global->LDS, 16B per active lane; LDS dst = uniform base + lane*16
    __builtin_amdgcn_global_load_lds((glb_f*)(uintptr_t)g,
                                     (lds_f*)(uintptr_t)l, 16, 0, 0);
}

__device__ __forceinline__ int ld_acq(int* p) {
    return __hip_atomic_load(p, __ATOMIC_ACQUIRE, __HIP_MEMORY_SCOPE_WORKGROUP);
}
__device__ __forceinline__ void st_rel(int* p, int v) {
    __hip_atomic_store(p, v, __ATOMIC_RELEASE, __HIP_MEMORY_SCOPE_WORKGROUP);
}
__device__ __forceinline__ void st_rlx(int* p, int v) {
    __hip_atomic_store(p, v, __ATOMIC_RELAXED, __HIP_MEMORY_SCOPE_WORKGROUP);
}

__global__ __launch_bounds__(256, 1)
void gr4j_kernel(const float2* __restrict__ pe_in,   // [T_TOTAL*NB] (p,e)
                 const float*  __restrict__ params,  // [NB,4]
                 float*        __restrict__ out)     // [(T_TOTAL-NWARM)*NB]
{
    const int lane = threadIdx.x & 63;
    const int wid  = threadIdx.x >> 6;
    const int b    = blockIdx.x * 64 + lane;

    __shared__ float4 inbuf[4][CH][32];              // 22.5 KB input ring
    __shared__ float  prring[4][CH * 64];            // 11.3 KB pr ring
    __shared__ float2 qring[4][CH * 64];             // 22.5 KB (q9,q1) ring
    __shared__ int in_ready;                         // chunks LDS-resident
    __shared__ int w1_done;                          // chunks s-chain done
    __shared__ int w2_done;                          // chunks conv done
    __shared__ int w3_done;                          // chunks routed/stored
    if (threadIdx.x == 0) { in_ready = 0; w1_done = 0; w2_done = 0; w3_done = 0; }
    __syncthreads();   // the only barrier: flag init (outside the pipeline)

    if (wid == 0) {
        // =============== w0: input staging, nothing else ===============
        // chunk c, step i: row t=11c+i. 32 lanes x float4 = 128 floats =
        // the block's 64 (p,e) pairs. Global float4 idx = t*1024+bx*32+lane.
        const float4* p4 = (const float4*)pe_in + (size_t)blockIdx.x * 32 + lane;
        const bool active = (lane < 32);

        // prologue: stage chunks 0,1 (22 ops in flight)
        if (active) {
            #pragma unroll
            for (int cc = 0; cc < 2; ++cc)
                #pragma unroll
                for (int i = 0; i < CH; ++i)
                    gl_lds_16((const float*)(p4 + (size_t)(cc * CH + i) * 1024),
                              (float*)&inbuf[cc][i][0]);
        }

        for (int c = 0; c <= NCHUNK - 3; ++c) {
            // slot (c+2)&3 reuse: w1 must be done with chunk c-2
            if (c >= 2) while (ld_acq(&w1_done) < c - 1) {}
            if (active) {
                const int slot = (c + 2) & 3;
                const float4* cb = p4 + (size_t)(c + 2) * CH * 1024;
                #pragma unroll
                for (int i = 0; i < CH; ++i)
                    gl_lds_16((const float*)(cb + (size_t)i * 1024),
                              (float*)&inbuf[slot][i][0]);
            }
            // newest chunk (c+2, 11 ops) may stay in flight; chunks <= c+1
            // are LDS-resident once vmcnt <= 11.
            asm volatile("s_waitcnt vmcnt(11)" ::: "memory");
            if (lane == 0) st_rlx(&in_ready, c + 2);
        }
        asm volatile("s_waitcnt vmcnt(0)" ::: "memory");
        if (lane == 0) st_rlx(&in_ready, NCHUNK);
    } else if (wid == 1) {
        // ================== w1: s-chain -> pr ==================
        const float x1 = 100.0f + params[b * 4 + 0] * 1100.0f;
        const float invx1 = __builtin_amdgcn_rcpf(x1);
        const float c49   = (4.0f / 9.0f) * invx1;
        const float c49_2 = c49 * c49;
        const float c4s   = c49_2 * c49_2;           // ((4/9)/x1)^4
        float s = 0.5f * x1;

        auto prod_step = [&](float p_, float e_) -> float {
            const float diff = p_ - e_;
            const float pn = fmaxf(diff, 0.0f);
            const float en = fmaxf(-diff, 0.0f);
            const float ap = pn * invx1;             // ~= tanh(pn/x1)
            const float ae = en * invx1;             // ~= tanh(en/x1)
            const float sx = s * invx1;
            const float dp = fmaf(sx, ap, 1.0f);
            const float de = fmaf(1.0f - sx, ae, 1.0f);
            const float n1 = fmaf(-sx, sx, 1.0f);
            const float nump = pn * n1;              // x1*(1-sx^2)*(pn/x1)
            const float nume = (sx * en) * (2.0f - sx);
            // rpe = 1/(dp*de), dp*de in [1,1.0202): cubic series, err<=u^4
            const float u  = fmaf(dp, de, -1.0f);
            const float t1 = 1.0f - u;
            const float t2 = fmaf(-u, t1, 1.0f);
            const float rpe = fmaf(-u, t2, 1.0f);    // 1-u+u^2-u^3
            const float a_ = nump * de;
            const float b_ = nume * dp;
            const float s2 = fmaf(a_ - b_, rpe, s);  // s - es + ps
            const float ps = a_ * rpe;
            const float s22 = s2 * s2;
            const float s24 = s22 * s22;
            const float z = c4s * s24;               // <= 0.039
            float w = fmaf(z, 15.0f / 128.0f, -5.0f / 32.0f);
            w = fmaf(z, w, 0.25f);
            const float perc = (s2 * z) * w;         // s2*(1-(1+z)^-.25)
            s = s2 - perc;
            return perc + (pn - ps);
        };

        for (int c = 0; c < NCHUNK; ++c) {
            while (ld_acq(&in_ready) < c + 1) {}
            if (c >= 4) while (ld_acq(&w2_done) < c - 3) {}
            const int slot = c & 3;
            // lane's (p,e) = float2 idx i*64+lane of the chunk's rows
            const float2* ib = (const float2*)&inbuf[slot][0][0];
            float2 pe[CH];
            #pragma unroll
            for (int i = 0; i < CH; ++i) pe[i] = ib[i * 64 + lane];
            float* dst = &prring[slot][lane];
            #pragma unroll
            for (int i = 0; i < CH; ++i)
                dst[i * 64] = prod_step(pe[i].x, pe[i].y);
            if (lane == 0) st_rel(&w1_done, c + 1);  // no vmem in w1: free
        }
    } else if (wid == 2) {
        // ================== w2: conv -> (q9,q1) ==================
        const float x4 = 1.1f + params[b * 4 + 3] * 1.8f;
        float u10, u11, u12, u20, u21, u22, u23, u24, u25;
        {
            float sh[3];
            #pragma unroll
            for (int j = 1; j <= 3; ++j)
                sh[j - 1] = powf(fminf((float)j / x4, 1.0f), 2.5f);
            u10 = sh[0]; u11 = sh[1] - sh[0]; u12 = sh[2] - sh[1];
            float s2h[6];
            #pragma unroll
            for (int j = 1; j <= 6; ++j) {
                float rr = (float)j / x4;
                s2h[j - 1] = ((float)j <= x4) ? 0.5f * powf(rr, 2.5f)
                           : 1.0f - 0.5f * powf(fmaxf(2.0f - rr, 0.0f), 2.5f);
            }
            u20 = s2h[0];          u21 = s2h[1] - s2h[0]; u22 = s2h[2] - s2h[1];
            u23 = s2h[3] - s2h[2]; u24 = s2h[4] - s2h[3]; u25 = s2h[5] - s2h[4];
        }
        float ph0 = 0.f, ph1 = 0.f, ph2 = 0.f, ph3 = 0.f, ph4 = 0.f;

        auto conv_step = [&](float pr) -> float2 {
            const float q9 = fmaf(u10, pr, fmaf(u11, ph0, u12 * ph1));
            const float q1 = fmaf(u20, pr, fmaf(u21, ph0, fmaf(u22, ph1,
                             fmaf(u23, ph2, fmaf(u24, ph3, u25 * ph4)))));
            ph4 = ph3; ph3 = ph2; ph2 = ph1; ph1 = ph0; ph0 = pr;
            return make_float2(q9, q1);
        };

        for (int c = 0; c < NCHUNK; ++c) {
            while (ld_acq(&w1_done) < c + 1) {}
            if (c >= 4) while (ld_acq(&w3_done) < c - 3) {}
            const int slot = c & 3;
            const float* src = &prring[slot][lane];
            float prr[CH];
            #pragma unroll
            for (int i = 0; i < CH; ++i) prr[i] = src[i * 64];
            float2* dst = &qring[slot][lane];
            if (c != 33) {
                #pragma unroll
                for (int i = 0; i < CH; ++i) dst[i * 64] = conv_step(prr[i]);
            } else {
                // chunk 33: t=363..373; reference restarts conv history at
                // t=365 (i==2). s,r carry over; conv history does not.
                #pragma unroll
                for (int i = 0; i < CH; ++i) {
                    if (i == 2) { ph0 = ph1 = ph2 = ph3 = ph4 = 0.0f; }
                    dst[i * 64] = conv_step(prr[i]);
                }
            }
            if (lane == 0) st_rel(&w2_done, c + 1);  // no vmem in w2: free
        }
    } else {
        // ================== w3: r-chain + store ==================
        const float x2 = -5.0f + params[b * 4 + 1] * 8.0f;
        const float x3 = 20.0f + params[b * 4 + 2] * 280.0f;
        const float invx3 = __builtin_amdgcn_rcpf(x3);
        const float gxc = x2 * invx3;

        // v(zeta) = (1+zeta)^{-1/8}, deg-16 Taylor about zeta0=1.5:
        // t = (zeta-1.5)/2.5 in [-0.6,0.6] for zeta in [0,3];
        // cf[k] = 2.5^{-1/8} * binom(-1/8,k), exact recurrence in double.
        float cf[17];
        {
            double bb = 1.0;                         // binom(-1/8,0)
            #pragma unroll
            for (int k2 = 0; k2 < 17; ++k2) {
                cf[k2] = (float)(0.8917795276 * bb); // 2.5^{-1/8} * b_k
                bb *= -((double)k2 + 0.125) / ((double)k2 + 1.0);
            }
        }

        float rx = 0.5f;                             // r/x3 (r0 = 0.5*x3)
        float h  = 0.70710678118f;                   // sqrt(rx)

        auto w3_step = [&](float2 qin) -> float {
            const float q9i = qin.x * invx3;
            const float h4  = rx * rx;               // rx = h^2
            const float h3  = rx * h;
            const float h7  = h3 * h4;
            const float gex = x2 * h7;               // x2*(r/x3)^3.5
            const float dd  = fmaf(gxc, h7, q9i);    // (q9+gex)/x3
            const float rx2 = fmaxf(rx + dd, 0.0f);  // r2/x3
            const float srt = __builtin_amdgcn_sqrtf(rx2);  // || with poly
            const float z2c = rx2 * rx2;
            const float zt  = z2c * z2c;             // (r2/x3)^4
            // deg-16 Estrin for v = (1+zt)^{-1/8}
            const float t   = (zt - 1.5f) * 0.4f;
            const float t2  = t * t;
            const float t4  = t2 * t2;
            const float t8  = t4 * t4;
            const float t16 = t8 * t8;
            const float p0 = fmaf(cf[1],  t, cf[0]);
            const float p1 = fmaf(cf[3],  t, cf[2]);
            const float p2 = fmaf(cf[5],  t, cf[4]);
            const float p3 = fmaf(cf[7],  t, cf[6]);
            const float p4 = fmaf(cf[9],  t, cf[8]);
            const float p5 = fmaf(cf[11], t, cf[10]);
            const float p6 = fmaf(cf[13], t, cf[12]);
            const float p7 = fmaf(cf[15], t, cf[14]);
            const float q0 = fmaf(p1, t2, p0);
            const float q1e = fmaf(p3, t2, p2);
            const float q2 = fmaf(p5, t2, p4);
            const float q3 = fmaf(p7, t2, p6);
            const float o0 = fmaf(q1e, t4, q0);
            const float o1 = fmaf(q3,  t4, q2);
            const float v15 = fmaf(o1, t8, o0);
            float v = fmaf(cf[16], t16, v15);
            if (__any(zt > 3.0f)) {
                // pathological basins (zeta>3, hard bound ~10): exact
                // (1+zt)^{-1/8}. Scalar branch: never taken in practice,
                // keeps the 3-trans chain OFF the critical path.
                const float ve = __builtin_amdgcn_rsqf(__builtin_amdgcn_sqrtf(
                                 __builtin_amdgcn_sqrtf(1.0f + zt)));
                v = (zt > 3.0f) ? ve : v;
            }
            const float w   = v * v;                 // (1+zt)^{-1/4}
            const float rxn = rx2 * w;               // r_next/x3
            const float qr  = x3 * (rx2 - rxn);
            h  = srt * v;                            // sqrt(rxn)
            rx = rxn;
            return qr + fmaxf(0.0f, qin.y + gex);
        };

        for (int c = 0; c < NCHUNK; ++c) {
            while (ld_acq(&w2_done) < c + 1) {}
            // Dump/real WAW ordering, one-time waits:
            //  c==33: dumps rows<=362 (chunks<=32) retired before real rows
            //         0..8 are issued this chunk.
            //  c==34: dumps 363,364 (chunk 33) retired before their real
            //         twins (chunk 66) are issued later in program order.
            if (c == 33 || c == 34)
                asm volatile("s_waitcnt vmcnt(0)" ::: "memory");
            const int slot = c & 3;
            const float2* src = &qring[slot][lane];
            float2 qq[CH];
            #pragma unroll
            for (int i = 0; i < CH; ++i) qq[i] = src[i * 64];
            if (c != 33) {
                // c<33: t=11c+i<=362 -> dump rows [t] (rewritten by
                // t'=365+row later, same wave, ordered by c==34 wait).
                // c>=34: rows t-365.
                float* ob = out + (size_t)((c < 33) ? 11 * c
                                                    : 11 * c - NWARM) * NB + b;
                #pragma unroll
                for (int i = 0; i < CH; ++i)
                    ob[(size_t)i * NB] = w3_step(qq[i]);
            } else {
                // chunk 33: i=0,1 -> dump rows 363,364; i>=2 -> real rows 0..8
                float* dumpb = out + (size_t)363 * NB + b;
                float* realb = out + b;
                #pragma unroll
                for (int i = 0; i < CH; ++i) {
                    const float q = w3_step(qq[i]);
                    if (i < 2) dumpb[(size_t)i * NB] = q;
                    else       realb[(size_t)(i - 2) * NB] = q;
                }
            }
            // qring reads retired (results consumed); flag must not drain
            // the global stores -> RELAXED + lgkmcnt only.
            asm volatile("s_waitcnt lgkmcnt(0)" ::: "memory");
            if (lane == 0) st_rlx(&w3_done, c + 1);
        }
    }
}

extern "C" void kernel_launch(void* const* d_in, const int* in_sizes, int n_in,
                              void* d_out, int out_size, void* d_ws, size_t ws_size,
                              hipStream_t stream) {
    const float2* pe_in  = (const float2*)d_in[0];   // p_and_e [4015,2048,2]
    const float*  params = (const float*)d_in[1];    // parameters [2048,4]
    float* out = (float*)d_out;                      // [3650,2048,1]
    (void)in_sizes; (void)n_in; (void)out_size; (void)d_ws; (void)ws_size;

    gr4j_kernel<<<dim3(NB / 64), dim3(256), 0, stream>>>(pe_in, params, out);
}

// Round 5
// 444.263 us; speedup vs baseline: 1.3306x; 1.3306x over previous
//
#include <hip/hip_runtime.h>

// GR4J daily hydrological model, round 11: branch-free de-transcendentalized
// r-chain. T=4015 steps, WARMUP=365, B=2048 basins, 32 blocks x 256 threads.
//
// R10 (poly routing + __any fallback branch) REGRESSED 313->517. Model fit
// across R9/R10: each stage wave is a single wave running a serial chain at
// ~4-5 cyc per dependent VALU edge, ~50 cyc per dependent trans op. R10's
// chain was short (~14 edges) -- the regression is the PER-STEP SCALAR
// BRANCH (taken in the common case => instruction-fetch redirect every
// step, 23 basic blocks per unrolled chunk, no cross-step scheduling) plus
// runtime double-precision coefficient init.
//
// R11: identical algebra, zero branches:
//  - w3: fallback deleted. Proven bound: rx<1 invariant (rxn =
//    rx2*(1+rx2^4)^-1/4 < 1 for ALL rx2), pn<=1, q9<=~1.05, |gex|<=3,
//    x3>=20 => rx2<=1.21 => zt<=2.2 < 3 = poly validity edge. Straight-line
//    deg-16 Estrin, coefficients as compile-time literals
//    (cf_k = 2.5^{-1/8} * binom(-1/8,k); v(0)=0.999993, v(1.5)=0.891780).
//  - w3 reorder: rxpq=rx+q9i off the h^7 path; t=fma(zt,0.4,-0.6).
//    Chain ~14 VALU edges + 1 sqrt in parallel (h_next = sqrt(rx2)*v).
//  - w1: u = sx*ap + (1-sx)*ae (drop ab cross term, <=1.1e-4) and
//    quadratic rpe = fma(u,u-1,1) (drop u^3 <= 8.4e-6). Chain ~13 edges.
//  - w0/w2 byte-identical to R9/R10.
//
// Pipeline (unchanged):
//   w0: input staging, global_load_lds size=16, counted vmcnt(11).
//   w1: s-chain -> pr (prring).
//   w2: 9-tap UH conv -> packed (q9,q1) (qring); t=365 history reset.
//   w3: r-chain + store.
// Flags: w1/w2 RELEASE (no vmem), w0/w3 RELAXED + explicit waitcnt.
// Dump/real WAW ordering: one-time vmcnt(0) in w3 at chunks 33, 34.
//
// Approximations (threshold 3.97e-2; absmax 7.8e-3 through R10):
//  - tanh(x) ~= x for x<=0.01; (1+z)^(-1/4) 3-term series in prod;
//  - rpe = 1/(dp*de) ~= 1-u+u^2, u = sx*ap+(1-sx)*ae (err ~1.1e-4);
//  - routing (1+zt)^(-1/8) deg-16 Taylor about 1.5, err <= ~1e-5 on [0,3].

#define T_TOTAL 4015
#define NWARM   365
#define NB      2048
#define CH      11          // pipeline chunk: 11 steps
#define NCHUNK  365         // 365 * 11 = 4015

typedef __attribute__((address_space(3))) float       lds_f;
typedef __attribute__((address_space(1))) const float glb_f;

__device__ __forceinline__ void gl_lds_16(const float* g, float* l) {
    // async global->LDS, 16B per active lane; LDS dst = uniform base + lane*16
    __builtin_amdgcn_global_load_lds((glb_f*)(uintptr_t)g,
                                     (lds_f*)(uintptr_t)l, 16, 0, 0);
}

__device__ __forceinline__ int ld_acq(int* p) {
    return __hip_atomic_load(p, __ATOMIC_ACQUIRE, __HIP_MEMORY_SCOPE_WORKGROUP);
}
__device__ __forceinline__ void st_rel(int* p, int v) {
    __hip_atomic_store(p, v, __ATOMIC_RELEASE, __HIP_MEMORY_SCOPE_WORKGROUP);
}
__device__ __forceinline__ void st_rlx(int* p, int v) {
    __hip_atomic_store(p, v, __ATOMIC_RELAXED, __HIP_MEMORY_SCOPE_WORKGROUP);
}

__global__ __launch_bounds__(256, 1)
void gr4j_kernel(const float2* __restrict__ pe_in,   // [T_TOTAL*NB] (p,e)
                 const float*  __restrict__ params,  // [NB,4]
                 float*        __restrict__ out)     // [(T_TOTAL-NWARM)*NB]
{
    const int lane = threadIdx.x & 63;
    const int wid  = threadIdx.x >> 6;
    const int b    = blockIdx.x * 64 + lane;

    __shared__ float4 inbuf[4][CH][32];              // 22.5 KB input ring
    __shared__ float  prring[4][CH * 64];            // 11.3 KB pr ring
    __shared__ float2 qring[4][CH * 64];             // 22.5 KB (q9,q1) ring
    __shared__ int in_ready;                         // chunks LDS-resident
    __shared__ int w1_done;                          // chunks s-chain done
    __shared__ int w2_done;                          // chunks conv done
    __shared__ int w3_done;                          // chunks routed/stored
    if (threadIdx.x == 0) { in_ready = 0; w1_done = 0; w2_done = 0; w3_done = 0; }
    __syncthreads();   // the only barrier: flag init (outside the pipeline)

    if (wid == 0) {
        // =============== w0: input staging, nothing else ===============
        // chunk c, step i: row t=11c+i. 32 lanes x float4 = 128 floats =
        // the block's 64 (p,e) pairs. Global float4 idx = t*1024+bx*32+lane.
        const float4* p4 = (const float4*)pe_in + (size_t)blockIdx.x * 32 + lane;
        const bool active = (lane < 32);

        // prologue: stage chunks 0,1 (22 ops in flight)
        if (active) {
            #pragma unroll
            for (int cc = 0; cc < 2; ++cc)
                #pragma unroll
                for (int i = 0; i < CH; ++i)
                    gl_lds_16((const float*)(p4 + (size_t)(cc * CH + i) * 1024),
                              (float*)&inbuf[cc][i][0]);
        }

        for (int c = 0; c <= NCHUNK - 3; ++c) {
            // slot (c+2)&3 reuse: w1 must be done with chunk c-2
            if (c >= 2) while (ld_acq(&w1_done) < c - 1) {}
            if (active) {
                const int slot = (c + 2) & 3;
                const float4* cb = p4 + (size_t)(c + 2) * CH * 1024;
                #pragma unroll
                for (int i = 0; i < CH; ++i)
                    gl_lds_16((const float*)(cb + (size_t)i * 1024),
                              (float*)&inbuf[slot][i][0]);
            }
            // newest chunk (c+2, 11 ops) may stay in flight; chunks <= c+1
            // are LDS-resident once vmcnt <= 11.
            asm volatile("s_waitcnt vmcnt(11)" ::: "memory");
            if (lane == 0) st_rlx(&in_ready, c + 2);
        }
        asm volatile("s_waitcnt vmcnt(0)" ::: "memory");
        if (lane == 0) st_rlx(&in_ready, NCHUNK);
    } else if (wid == 1) {
        // ================== w1: s-chain -> pr ==================
        const float x1 = 100.0f + params[b * 4 + 0] * 1100.0f;
        const float invx1 = __builtin_amdgcn_rcpf(x1);
        const float c49   = (4.0f / 9.0f) * invx1;
        const float c49_2 = c49 * c49;
        const float c4s   = c49_2 * c49_2;           // ((4/9)/x1)^4
        float s = 0.5f * x1;

        auto prod_step = [&](float p_, float e_) -> float {
            const float diff = p_ - e_;
            const float pn = fmaxf(diff, 0.0f);
            const float en = fmaxf(-diff, 0.0f);
            const float ap = pn * invx1;             // ~= tanh(pn/x1)
            const float ae = en * invx1;             // ~= tanh(en/x1)
            const float sx = s * invx1;              // [1]
            const float omsx = 1.0f - sx;            // [2]
            const float dp = fmaf(sx, ap, 1.0f);     // [2]
            const float de = fmaf(omsx, ae, 1.0f);   // [3]
            const float n1 = fmaf(-sx, sx, 1.0f);    // [2]
            const float nump = pn * n1;              // [3]
            const float nume = (sx * en) * (2.0f - sx);  // [3]
            // rpe = 1/(dp*de): u = sx*ap + (1-sx)*ae (ab term dropped,
            // |ab|<=1.1e-4); rpe ~= 1-u+u^2 (u<=0.0203, u^3<=8.4e-6).
            const float a_r = sx * ap;               // [2]
            const float b_r = omsx * ae;             // [3]
            const float u   = a_r + b_r;             // [4]
            const float rpe = fmaf(u, u - 1.0f, 1.0f);   // [6]
            const float a_ = nump * de;              // [4]
            const float b_ = nume * dp;              // [4]
            const float s2 = fmaf(a_ - b_, rpe, s);  // [7]  s - es + ps
            const float ps = a_ * rpe;               // off-chain (pr)
            const float s22 = s2 * s2;               // [8]
            const float s24 = s22 * s22;             // [9]
            const float z = c4s * s24;               // [10] <= 0.039
            float w = fmaf(z, 15.0f / 128.0f, -5.0f / 32.0f);  // [11]
            w = fmaf(z, w, 0.25f);                   // [12]
            const float s2z = s2 * z;                // [11]
            const float perc = s2z * w;              // [13] s2*(1-(1+z)^-.25)
            s = s2 - perc;                           // [14]
            return perc + (pn - ps);
        };

        for (int c = 0; c < NCHUNK; ++c) {
            while (ld_acq(&in_ready) < c + 1) {}
            if (c >= 4) while (ld_acq(&w2_done) < c - 3) {}
            const int slot = c & 3;
            // lane's (p,e) = float2 idx i*64+lane of the chunk's rows
            const float2* ib = (const float2*)&inbuf[slot][0][0];
            float2 pe[CH];
            #pragma unroll
            for (int i = 0; i < CH; ++i) pe[i] = ib[i * 64 + lane];
            float* dst = &prring[slot][lane];
            #pragma unroll
            for (int i = 0; i < CH; ++i)
                dst[i * 64] = prod_step(pe[i].x, pe[i].y);
            if (lane == 0) st_rel(&w1_done, c + 1);  // no vmem in w1: free
        }
    } else if (wid == 2) {
        // ================== w2: conv -> (q9,q1) ==================
        const float x4 = 1.1f + params[b * 4 + 3] * 1.8f;
        float u10, u11, u12, u20, u21, u22, u23, u24, u25;
        {
            float sh[3];
            #pragma unroll
            for (int j = 1; j <= 3; ++j)
                sh[j - 1] = powf(fminf((float)j / x4, 1.0f), 2.5f);
            u10 = sh[0]; u11 = sh[1] - sh[0]; u12 = sh[2] - sh[1];
            float s2h[6];
            #pragma unroll
            for (int j = 1; j <= 6; ++j) {
                float rr = (float)j / x4;
                s2h[j - 1] = ((float)j <= x4) ? 0.5f * powf(rr, 2.5f)
                           : 1.0f - 0.5f * powf(fmaxf(2.0f - rr, 0.0f), 2.5f);
            }
            u20 = s2h[0];          u21 = s2h[1] - s2h[0]; u22 = s2h[2] - s2h[1];
            u23 = s2h[3] - s2h[2]; u24 = s2h[4] - s2h[3]; u25 = s2h[5] - s2h[4];
        }
        float ph0 = 0.f, ph1 = 0.f, ph2 = 0.f, ph3 = 0.f, ph4 = 0.f;

        auto conv_step = [&](float pr) -> float2 {
            const float q9 = fmaf(u10, pr, fmaf(u11, ph0, u12 * ph1));
            const float q1 = fmaf(u20, pr, fmaf(u21, ph0, fmaf(u22, ph1,
                             fmaf(u23, ph2, fmaf(u24, ph3, u25 * ph4)))));
            ph4 = ph3; ph3 = ph2; ph2 = ph1; ph1 = ph0; ph0 = pr;
            return make_float2(q9, q1);
        };

        for (int c = 0; c < NCHUNK; ++c) {
            while (ld_acq(&w1_done) < c + 1) {}
            if (c >= 4) while (ld_acq(&w3_done) < c - 3) {}
            const int slot = c & 3;
            const float* src = &prring[slot][lane];
            float prr[CH];
            #pragma unroll
            for (int i = 0; i < CH; ++i) prr[i] = src[i * 64];
            float2* dst = &qring[slot][lane];
            if (c != 33) {
                #pragma unroll
                for (int i = 0; i < CH; ++i) dst[i * 64] = conv_step(prr[i]);
            } else {
                // chunk 33: t=363..373; reference restarts conv history at
                // t=365 (i==2). s,r carry over; conv history does not.
                #pragma unroll
                for (int i = 0; i < CH; ++i) {
                    if (i == 2) { ph0 = ph1 = ph2 = ph3 = ph4 = 0.0f; }
                    dst[i * 64] = conv_step(prr[i]);
                }
            }
            if (lane == 0) st_rel(&w2_done, c + 1);  // no vmem in w2: free
        }
    } else {
        // ================== w3: r-chain + store ==================
        const float x2 = -5.0f + params[b * 4 + 1] * 8.0f;
        const float x3 = 20.0f + params[b * 4 + 2] * 280.0f;
        const float invx3 = __builtin_amdgcn_rcpf(x3);
        const float gxc = x2 * invx3;

        // v(zt) = (1+zt)^{-1/8}, deg-16 Taylor about 1.5, t=(zt-1.5)*0.4:
        // cf_k = 2.5^{-1/8} * binom(-1/8,k), compile-time literals.
        // Validity zt in [0,3]; proven runtime bound zt <= 2.2.
        constexpr float cf0  =  0.8917797f,  cf1  = -0.11147246f;
        constexpr float cf2  =  0.06270282f, cf3  = -0.04441468f;
        constexpr float cf4  =  0.03469894f, cf5  = -0.02862669f;
        constexpr float cf6  =  0.02445219f, cf7  = -0.02139546f;
        constexpr float cf8  =  0.01905534f, cf9  = -0.01720275f;
        constexpr float cf10 =  0.01569753f, cf11 = -0.01444885f;
        constexpr float cf12 =  0.01339529f, cf13 = -0.01249372f;
        constexpr float cf14 =  0.01171288f, cf15 = -0.01102958f;
        constexpr float cf16 =  0.01042645f;

        float rx = 0.5f;                             // r/x3 (r0 = 0.5*x3)
        float h  = 0.70710678f;                      // sqrt(rx)

        auto w3_step = [&](float2 qin) -> float {
            const float q9i  = qin.x * invx3;        // off-chain
            const float rxpq = rx + q9i;             // [1]
            const float h4   = rx * rx;              // [1]
            const float h3   = rx * h;               // [1]
            const float h7   = h3 * h4;              // [2]  (r/x3)^3.5
            const float gex  = x2 * h7;              // [3]  off-chain (qd)
            const float rx2  = fmaxf(fmaf(gxc, h7, rxpq), 0.0f);   // [4]
            const float srt  = __builtin_amdgcn_sqrtf(rx2);  // || with poly
            const float z2c  = rx2 * rx2;            // [5]
            const float zt   = z2c * z2c;            // [6]  (r2/x3)^4 <= 2.2
            const float t    = fmaf(zt, 0.4f, -0.6f);        // [7]
            const float t2   = t * t;                // [8]
            const float t4   = t2 * t2;              // [9]
            const float t8   = t4 * t4;              // [10]
            const float t16  = t8 * t8;              // [11]
            const float p0 = fmaf(cf1,  t, cf0);     // [8]
            const float p1 = fmaf(cf3,  t, cf2);
            const float p2 = fmaf(cf5,  t, cf4);
            const float p3 = fmaf(cf7,  t, cf6);
            const float p4 = fmaf(cf9,  t, cf8);
            const float p5 = fmaf(cf11, t, cf10);
            const float p6 = fmaf(cf13, t, cf12);
            const float p7 = fmaf(cf15, t, cf14);
            const float q0 = fmaf(p1, t2, p0);       // [9]
            const float q1e = fmaf(p3, t2, p2);
            const float q2 = fmaf(p5, t2, p4);
            const float q3 = fmaf(p7, t2, p6);
            const float o0 = fmaf(q1e, t4, q0);      // [10]
            const float o1 = fmaf(q3,  t4, q2);
            const float v15 = fmaf(o1, t8, o0);      // [11]
            const float v   = fmaf(cf16, t16, v15);  // [12] (1+zt)^{-1/8}
            const float w   = v * v;                 // [13] (1+zt)^{-1/4}
            const float rxn = rx2 * w;               // [14] r_next/x3
            const float qr  = x3 * (rx2 - rxn);      // off-chain
            h  = srt * v;                            // [13] sqrt(rxn)
            rx = rxn;
            return qr + fmaxf(0.0f, qin.y + gex);
        };

        for (int c = 0; c < NCHUNK; ++c) {
            while (ld_acq(&w2_done) < c + 1) {}
            // Dump/real WAW ordering, one-time waits:
            //  c==33: dumps rows<=362 (chunks<=32) retired before real rows
            //         0..8 are issued this chunk.
            //  c==34: dumps 363,364 (chunk 33) retired before their real
            //         twins (chunk 66) are issued later in program order.
            if (c == 33 || c == 34)
                asm volatile("s_waitcnt vmcnt(0)" ::: "memory");
            const int slot = c & 3;
            const float2* src = &qring[slot][lane];
            float2 qq[CH];
            #pragma unroll
            for (int i = 0; i < CH; ++i) qq[i] = src[i * 64];
            if (c != 33) {
                // c<33: t=11c+i<=362 -> dump rows [t] (rewritten by
                // t'=365+row later, same wave, ordered by c==34 wait).
                // c>=34: rows t-365.
                float* ob = out + (size_t)((c < 33) ? 11 * c
                                                    : 11 * c - NWARM) * NB + b;
                #pragma unroll
                for (int i = 0; i < CH; ++i)
                    ob[(size_t)i * NB] = w3_step(qq[i]);
            } else {
                // chunk 33: i=0,1 -> dump rows 363,364; i>=2 -> real rows 0..8
                float* dumpb = out + (size_t)363 * NB + b;
                float* realb = out + b;
                #pragma unroll
                for (int i = 0; i < CH; ++i) {
                    const float q = w3_step(qq[i]);
                    if (i < 2) dumpb[(size_t)i * NB] = q;
                    else       realb[(size_t)(i - 2) * NB] = q;
                }
            }
            // qring reads retired (results consumed); flag must not drain
            // the global stores -> RELAXED + lgkmcnt only.
            asm volatile("s_waitcnt lgkmcnt(0)" ::: "memory");
            if (lane == 0) st_rlx(&w3_done, c + 1);
        }
    }
}

extern "C" void kernel_launch(void* const* d_in, const int* in_sizes, int n_in,
                              void* d_out, int out_size, void* d_ws, size_t ws_size,
                              hipStream_t stream) {
    const float2* pe_in  = (const float2*)d_in[0];   // p_and_e [4015,2048,2]
    const float*  params = (const float*)d_in[1];    // parameters [2048,4]
    float* out = (float*)d_out;                      // [3650,2048,1]
    (void)in_sizes; (void)n_in; (void)out_size; (void)d_ws; (void)ws_size;

    gr4j_kernel<<<dim3(NB / 64), dim3(256), 0, stream>>>(pe_in, params, out);
}

// Round 6
// 378.513 us; speedup vs baseline: 1.5617x; 1.1737x over previous
//
#include <hip/hip_runtime.h>

// GR4J daily hydrological model, round 12: instruction-count diet on the
// wall wave. T=4015 steps, WARMUP=365, B=2048 basins, 32 blk x 256 thr.
//
// Model update (fits R5,R7,R8,R9,R11 within ~10%): a LONE wave on a CDNA4
// SIMD issues ~1 instruction per 4 cycles (CU front-end cadence); dep
// latency hides under it. Wall time = 4 cyc x (inst count of heaviest
// wave). R11's poly ADDED ~25 insts to w3 to remove chain latency that
// was already hidden -> 313->367 regression vs R9. Fix: minimize insts.
//
// R12 (structure identical to R11, arithmetic slimmed):
//  - w3 poly deg-16 -> deg-9. Tighter proven range: fixpoint of
//    rxn = rx2*(1+rx2^4)^-1/4 with q9i<=0.105, gex/x3<=0.15*rx^3.5 gives
//    rx2<=1.08 => zt<=1.4. Taylor about 0.7 (u=(zt-0.7)/1.7, |u|<=0.412):
//    err ~1.5e-6. Endpoints hand-checked: v(0)=1.000006, v(1.4)=0.896337
//    (exact 0.896341).
//  - drop fmax(rx2,0): rx2 = rx(1-0.25 rx^2.5)+q9i > 0 strictly
//    (pr>0 strictly because perc>0 => q9i>0; rx>0 inductively, rxn=h'^2).
//  - rxn = h'*h', h' = srt*v  (replaces w=v^2; rxn=rx2*w).
//  - q9i premul moved to w2 FOR FREE: invx3 folded into UH1 ordinates
//    at init; w2 ships (q9/x3, q1). w3 sheds 1 inst.
//  - w1: u = (dp+de)-2 replaces recomputing sx*ap + (1-sx)*ae (already
//    inside dp,de). Exact in real arithmetic.
// w3: ~47 -> ~32 insts/step. Predicted wall ~128-135 cyc/step.
//
// Pipeline (unchanged):
//   w0: input staging, global_load_lds size=16, counted vmcnt(11).
//   w1: s-chain -> pr (prring).
//   w2: 9-tap UH conv -> packed (q9/x3, q1) (qring); t=365 history reset.
//   w3: r-chain + store.
// Flags: w1/w2 RELEASE (no vmem), w0/w3 RELAXED + explicit waitcnt.
// Dump/real WAW ordering: one-time vmcnt(0) in w3 at chunks 33, 34.
//
// Approximations (threshold 3.97e-2; absmax 7.8e-3 through R11):
//  - tanh(x) ~= x for x<=0.01; (1+z)^(-1/4) 3-term series in prod;
//  - rpe = 1/(dp*de) ~= 1-u+u^2, u = dp+de-2 (err ~1e-4);
//  - routing (1+zt)^(-1/8) deg-9 Taylor about 0.7, err <= ~4e-6 on [0,1.4].

#define T_TOTAL 4015
#define NWARM   365
#define NB      2048
#define CH      11          // pipeline chunk: 11 steps
#define NCHUNK  365         // 365 * 11 = 4015

typedef __attribute__((address_space(3))) float       lds_f;
typedef __attribute__((address_space(1))) const float glb_f;

__device__ __forceinline__ void gl_lds_16(const float* g, float* l) {
    // async global->LDS, 16B per active lane; LDS dst = uniform base + lane*16
    __builtin_amdgcn_global_load_lds((glb_f*)(uintptr_t)g,
                                     (lds_f*)(uintptr_t)l, 16, 0, 0);
}

__device__ __forceinline__ int ld_acq(int* p) {
    return __hip_atomic_load(p, __ATOMIC_ACQUIRE, __HIP_MEMORY_SCOPE_WORKGROUP);
}
__device__ __forceinline__ void st_rel(int* p, int v) {
    __hip_atomic_store(p, v, __ATOMIC_RELEASE, __HIP_MEMORY_SCOPE_WORKGROUP);
}
__device__ __forceinline__ void st_rlx(int* p, int v) {
    __hip_atomic_store(p, v, __ATOMIC_RELAXED, __HIP_MEMORY_SCOPE_WORKGROUP);
}

__global__ __launch_bounds__(256, 1)
void gr4j_kernel(const float2* __restrict__ pe_in,   // [T_TOTAL*NB] (p,e)
                 const float*  __restrict__ params,  // [NB,4]
                 float*        __restrict__ out)     // [(T_TOTAL-NWARM)*NB]
{
    const int lane = threadIdx.x & 63;
    const int wid  = threadIdx.x >> 6;
    const int b    = blockIdx.x * 64 + lane;

    __shared__ float4 inbuf[4][CH][32];              // 22.5 KB input ring
    __shared__ float  prring[4][CH * 64];            // 11.3 KB pr ring
    __shared__ float2 qring[4][CH * 64];             // 22.5 KB (q9i,q1) ring
    __shared__ int in_ready;                         // chunks LDS-resident
    __shared__ int w1_done;                          // chunks s-chain done
    __shared__ int w2_done;                          // chunks conv done
    __shared__ int w3_done;                          // chunks routed/stored
    if (threadIdx.x == 0) { in_ready = 0; w1_done = 0; w2_done = 0; w3_done = 0; }
    __syncthreads();   // the only barrier: flag init (outside the pipeline)

    if (wid == 0) {
        // =============== w0: input staging, nothing else ===============
        // chunk c, step i: row t=11c+i. 32 lanes x float4 = 128 floats =
        // the block's 64 (p,e) pairs. Global float4 idx = t*1024+bx*32+lane.
        const float4* p4 = (const float4*)pe_in + (size_t)blockIdx.x * 32 + lane;
        const bool active = (lane < 32);

        // prologue: stage chunks 0,1 (22 ops in flight)
        if (active) {
            #pragma unroll
            for (int cc = 0; cc < 2; ++cc)
                #pragma unroll
                for (int i = 0; i < CH; ++i)
                    gl_lds_16((const float*)(p4 + (size_t)(cc * CH + i) * 1024),
                              (float*)&inbuf[cc][i][0]);
        }

        for (int c = 0; c <= NCHUNK - 3; ++c) {
            // slot (c+2)&3 reuse: w1 must be done with chunk c-2
            if (c >= 2) while (ld_acq(&w1_done) < c - 1) {}
            if (active) {
                const int slot = (c + 2) & 3;
                const float4* cb = p4 + (size_t)(c + 2) * CH * 1024;
                #pragma unroll
                for (int i = 0; i < CH; ++i)
                    gl_lds_16((const float*)(cb + (size_t)i * 1024),
                              (float*)&inbuf[slot][i][0]);
            }
            // newest chunk (c+2, 11 ops) may stay in flight; chunks <= c+1
            // are LDS-resident once vmcnt <= 11.
            asm volatile("s_waitcnt vmcnt(11)" ::: "memory");
            if (lane == 0) st_rlx(&in_ready, c + 2);
        }
        asm volatile("s_waitcnt vmcnt(0)" ::: "memory");
        if (lane == 0) st_rlx(&in_ready, NCHUNK);
    } else if (wid == 1) {
        // ================== w1: s-chain -> pr ==================
        const float x1 = 100.0f + params[b * 4 + 0] * 1100.0f;
        const float invx1 = __builtin_amdgcn_rcpf(x1);
        const float c49   = (4.0f / 9.0f) * invx1;
        const float c49_2 = c49 * c49;
        const float c4s   = c49_2 * c49_2;           // ((4/9)/x1)^4
        float s = 0.5f * x1;

        auto prod_step = [&](float p_, float e_) -> float {
            const float diff = p_ - e_;
            const float pn = fmaxf(diff, 0.0f);
            const float en = fmaxf(-diff, 0.0f);
            const float ap = pn * invx1;             // ~= tanh(pn/x1)
            const float ae = en * invx1;             // ~= tanh(en/x1)
            const float sx = s * invx1;
            const float omsx = 1.0f - sx;
            const float dp = fmaf(sx, ap, 1.0f);
            const float de = fmaf(omsx, ae, 1.0f);
            const float n1 = fmaf(-sx, sx, 1.0f);
            const float nump = pn * n1;
            const float nume = (sx * en) * (2.0f - sx);
            // rpe = 1/(dp*de): u = dp+de-2 (= sx*ap+(1-sx)*ae exactly;
            // ab cross term dropped, <=1.1e-4); rpe ~= 1-u+u^2.
            const float u   = (dp + de) - 2.0f;
            const float rpe = fmaf(u, u - 1.0f, 1.0f);
            const float a_ = nump * de;
            const float b_ = nume * dp;
            const float s2 = fmaf(a_ - b_, rpe, s);  // s - es + ps
            const float ps = a_ * rpe;               // off-chain (pr)
            const float s22 = s2 * s2;
            const float s24 = s22 * s22;
            const float z = c4s * s24;               // <= 0.039
            float w = fmaf(z, 15.0f / 128.0f, -5.0f / 32.0f);
            w = fmaf(z, w, 0.25f);
            const float s2z = s2 * z;
            const float perc = s2z * w;              // s2*(1-(1+z)^-.25)
            s = s2 - perc;
            return perc + (pn - ps);
        };

        for (int c = 0; c < NCHUNK; ++c) {
            while (ld_acq(&in_ready) < c + 1) {}
            if (c >= 4) while (ld_acq(&w2_done) < c - 3) {}
            const int slot = c & 3;
            // lane's (p,e) = float2 idx i*64+lane of the chunk's rows
            const float2* ib = (const float2*)&inbuf[slot][0][0];
            float2 pe[CH];
            #pragma unroll
            for (int i = 0; i < CH; ++i) pe[i] = ib[i * 64 + lane];
            float* dst = &prring[slot][lane];
            #pragma unroll
            for (int i = 0; i < CH; ++i)
                dst[i * 64] = prod_step(pe[i].x, pe[i].y);
            if (lane == 0) st_rel(&w1_done, c + 1);  // no vmem in w1: free
        }
    } else if (wid == 2) {
        // ========== w2: conv -> (q9/x3, q1); invx3 folded in UH1 ==========
        const float x3 = 20.0f + params[b * 4 + 2] * 280.0f;
        const float x4 = 1.1f  + params[b * 4 + 3] * 1.8f;
        const float invx3 = __builtin_amdgcn_rcpf(x3);
        float u10, u11, u12, u20, u21, u22, u23, u24, u25;
        {
            float sh[3];
            #pragma unroll
            for (int j = 1; j <= 3; ++j)
                sh[j - 1] = powf(fminf((float)j / x4, 1.0f), 2.5f);
            // fold invx3 into UH1 ordinates: w2 ships q9/x3 directly
            u10 = sh[0] * invx3;
            u11 = (sh[1] - sh[0]) * invx3;
            u12 = (sh[2] - sh[1]) * invx3;
            float s2h[6];
            #pragma unroll
            for (int j = 1; j <= 6; ++j) {
                float rr = (float)j / x4;
                s2h[j - 1] = ((float)j <= x4) ? 0.5f * powf(rr, 2.5f)
                           : 1.0f - 0.5f * powf(fmaxf(2.0f - rr, 0.0f), 2.5f);
            }
            u20 = s2h[0];          u21 = s2h[1] - s2h[0]; u22 = s2h[2] - s2h[1];
            u23 = s2h[3] - s2h[2]; u24 = s2h[4] - s2h[3]; u25 = s2h[5] - s2h[4];
        }
        float ph0 = 0.f, ph1 = 0.f, ph2 = 0.f, ph3 = 0.f, ph4 = 0.f;

        auto conv_step = [&](float pr) -> float2 {
            const float q9i = fmaf(u10, pr, fmaf(u11, ph0, u12 * ph1));
            const float q1 = fmaf(u20, pr, fmaf(u21, ph0, fmaf(u22, ph1,
                             fmaf(u23, ph2, fmaf(u24, ph3, u25 * ph4)))));
            ph4 = ph3; ph3 = ph2; ph2 = ph1; ph1 = ph0; ph0 = pr;
            return make_float2(q9i, q1);
        };

        for (int c = 0; c < NCHUNK; ++c) {
            while (ld_acq(&w1_done) < c + 1) {}
            if (c >= 4) while (ld_acq(&w3_done) < c - 3) {}
            const int slot = c & 3;
            const float* src = &prring[slot][lane];
            float prr[CH];
            #pragma unroll
            for (int i = 0; i < CH; ++i) prr[i] = src[i * 64];
            float2* dst = &qring[slot][lane];
            if (c != 33) {
                #pragma unroll
                for (int i = 0; i < CH; ++i) dst[i * 64] = conv_step(prr[i]);
            } else {
                // chunk 33: t=363..373; reference restarts conv history at
                // t=365 (i==2). s,r carry over; conv history does not.
                #pragma unroll
                for (int i = 0; i < CH; ++i) {
                    if (i == 2) { ph0 = ph1 = ph2 = ph3 = ph4 = 0.0f; }
                    dst[i * 64] = conv_step(prr[i]);
                }
            }
            if (lane == 0) st_rel(&w2_done, c + 1);  // no vmem in w2: free
        }
    } else {
        // ================== w3: r-chain + store ==================
        const float x2 = -5.0f + params[b * 4 + 1] * 8.0f;
        const float x3 = 20.0f + params[b * 4 + 2] * 280.0f;
        const float invx3 = __builtin_amdgcn_rcpf(x3);

        // v(zt) = (1+zt)^{-1/8}, deg-9 Taylor about 0.7, u=(zt-0.7)/1.7:
        // cf_k = 1.7^{-1/8} * binom(-1/8,k) / 1.7^k ... expressed as
        // cf_k = 0.935824 * b_k with b_k the binomial coeffs; u in
        // [-0.412, 0.412] for zt in [0,1.4] (proven bound zt<=1.4).
        constexpr float cf0 =  0.9358240f;
        constexpr float cf1 = -0.1169780f;
        constexpr float cf2 =  0.0658002f;
        constexpr float cf3 = -0.0466083f;
        constexpr float cf4 =  0.0364132f;
        constexpr float cf5 = -0.0300409f;
        constexpr float cf6 =  0.0256597f;
        constexpr float cf7 = -0.0224527f;
        constexpr float cf8 =  0.0199967f;
        constexpr float cf9 = -0.0180526f;
        constexpr float uscale = 0.5882353f;         // 1/1.7
        constexpr float ubias  = -0.4117647f;        // -0.7/1.7

        float rx = 0.5f;                             // r/x3 (r0 = 0.5*x3)
        float h  = 0.70710678f;                      // sqrt(rx)

        auto w3_step = [&](float2 qin) -> float {
            const float rxpq = rx + qin.x;           // qin.x = q9/x3
            const float h4   = rx * rx;
            const float h3   = rx * h;
            const float h7   = h3 * h4;              // (r/x3)^3.5
            const float gex  = x2 * h7;
            const float rx2  = fmaf(gex, invx3, rxpq);   // >0 proven
            const float srt  = __builtin_amdgcn_sqrtf(rx2);  // || with poly
            const float z2c  = rx2 * rx2;
            const float zt   = z2c * z2c;            // (r2/x3)^4 <= 1.4
            const float u    = fmaf(zt, uscale, ubias);
            const float u2   = u * u;
            const float u4   = u2 * u2;
            const float u8   = u4 * u4;
            const float p0 = fmaf(cf1, u, cf0);
            const float p1 = fmaf(cf3, u, cf2);
            const float p2 = fmaf(cf5, u, cf4);
            const float p3 = fmaf(cf7, u, cf6);
            const float p4 = fmaf(cf9, u, cf8);
            const float q0 = fmaf(p1, u2, p0);
            const float q1p = fmaf(p3, u2, p2);
            const float r0 = fmaf(q1p, u4, q0);
            const float v  = fmaf(p4, u8, r0);       // (1+zt)^{-1/8}
            const float hn = srt * v;                // sqrt(rxn)
            const float rxn = hn * hn;               // r_next/x3
            const float qr  = x3 * (rx2 - rxn);
            h  = hn;
            rx = rxn;
            return qr + fmaxf(0.0f, qin.y + gex);
        };

        for (int c = 0; c < NCHUNK; ++c) {
            while (ld_acq(&w2_done) < c + 1) {}
            // Dump/real WAW ordering, one-time waits:
            //  c==33: dumps rows<=362 (chunks<=32) retired before real rows
            //         0..8 are issued this chunk.
            //  c==34: dumps 363,364 (chunk 33) retired before their real
            //         twins (chunk 66) are issued later in program order.
            if (c == 33 || c == 34)
                asm volatile("s_waitcnt vmcnt(0)" ::: "memory");
            const int slot = c & 3;
            const float2* src = &qring[slot][lane];
            float2 qq[CH];
            #pragma unroll
            for (int i = 0; i < CH; ++i) qq[i] = src[i * 64];
            if (c != 33) {
                // c<33: t=11c+i<=362 -> dump rows [t] (rewritten by
                // t'=365+row later, same wave, ordered by c==34 wait).
                // c>=34: rows t-365.
                float* ob = out + (size_t)((c < 33) ? 11 * c
                                                    : 11 * c - NWARM) * NB + b;
                #pragma unroll
                for (int i = 0; i < CH; ++i)
                    ob[(size_t)i * NB] = w3_step(qq[i]);
            } else {
                // chunk 33: i=0,1 -> dump rows 363,364; i>=2 -> real rows 0..8
                float* dumpb = out + (size_t)363 * NB + b;
                float* realb = out + b;
                #pragma unroll
                for (int i = 0; i < CH; ++i) {
                    const float q = w3_step(qq[i]);
                    if (i < 2) dumpb[(size_t)i * NB] = q;
                    else       realb[(size_t)(i - 2) * NB] = q;
                }
            }
            // qring reads retired (results consumed); flag must not drain
            // the global stores -> RELAXED + lgkmcnt only.
            asm volatile("s_waitcnt lgkmcnt(0)" ::: "memory");
            if (lane == 0) st_rlx(&w3_done, c + 1);
        }
    }
}

extern "C" void kernel_launch(void* const* d_in, const int* in_sizes, int n_in,
                              void* d_out, int out_size, void* d_ws, size_t ws_size,
                              hipStream_t stream) {
    const float2* pe_in  = (const float2*)d_in[0];   // p_and_e [4015,2048,2]
    const float*  params = (const float*)d_in[1];    // parameters [2048,4]
    float* out = (float*)d_out;                      // [3650,2048,1]
    (void)in_sizes; (void)n_in; (void)out_size; (void)d_ws; (void)ws_size;

    gr4j_kernel<<<dim3(NB / 64), dim3(256), 0, stream>>>(pe_in, params, out);
}